// Round 16
// baseline (327.825 us; speedup 1.0000x reference)
//
#include <hip/hip_runtime.h>
#include <math.h>

#define D_IN 64
#define D_H 40
#define D_OUT 24
#define S_BITS 8
#define S_NODES 256      // nodes per bucket
#define CH 8192          // edges per passA/passB block
#define BMAX 512         // max buckets (n <= 131072)

typedef unsigned int u32;
typedef unsigned short u16;
typedef __attribute__((ext_vector_type(2))) float f32x2;

// ---------------- CSR build: atomic-free LDS multisplit ----------------
// passA: per-block histogram of dst buckets (bucket = dst >> 8).
// int4-vectorized edge reads: 4 edges/thread/iter, 1KB/wave-instr.
__global__ void passA(const int* __restrict__ dst, int* __restrict__ G,
                      int E, int B) {
    __shared__ int hist[BMAX];
    int tx = threadIdx.x;
    for (int i = tx; i < B; i += 256) hist[i] = 0;
    __syncthreads();
    int e0 = blockIdx.x * CH;
    int e1 = min(e0 + CH, E);
    for (int e = e0 + tx * 4; e < e1; e += 1024) {
        if (e + 4 <= e1) {
            int4 d4 = *(const int4*)(dst + e);
            atomicAdd(&hist[d4.x >> S_BITS], 1);
            atomicAdd(&hist[d4.y >> S_BITS], 1);
            atomicAdd(&hist[d4.z >> S_BITS], 1);
            atomicAdd(&hist[d4.w >> S_BITS], 1);
        } else {
            for (int q = e; q < e1; ++q)
                atomicAdd(&hist[dst[q] >> S_BITS], 1);
        }
    }
    __syncthreads();
    for (int i = tx; i < B; i += 256) G[(size_t)blockIdx.x * B + i] = hist[i];
}

// colscan: for bucket b, exclusive-scan G[i][b] over blocks i; total -> bktTotal.
__global__ void colscan(int* __restrict__ G, int* __restrict__ bktTotal,
                        int NB1, int B) {
    int b = blockIdx.x;
    int lane = threadIdx.x;      // 64 threads
    int carry = 0;
    for (int base = 0; base < NB1; base += 64) {
        int i = base + lane;
        int orig = (i < NB1) ? G[(size_t)i * B + b] : 0;
        int v = orig;
        #pragma unroll
        for (int d = 1; d < 64; d <<= 1) {
            int t = __shfl_up(v, d);
            if (lane >= d) v += t;
        }
        if (i < NB1) G[(size_t)i * B + b] = carry + v - orig;   // exclusive
        carry += __shfl(v, 63);
    }
    if (lane == 0) bktTotal[b] = carry;
}

// bucketscan: exclusive scan of bucket totals -> bktStart[0..B]; off[n] = E.
__global__ void bucketscan(const int* __restrict__ bktTotal,
                           int* __restrict__ bktStart, int* __restrict__ off,
                           int B, int E, int n) {
    int lane = threadIdx.x;
    int carry = 0;
    for (int base = 0; base < B; base += 64) {
        int i = base + lane;
        int orig = (i < B) ? bktTotal[i] : 0;
        int v = orig;
        #pragma unroll
        for (int d = 1; d < 64; d <<= 1) {
            int t = __shfl_up(v, d);
            if (lane >= d) v += t;
        }
        if (i < B) bktStart[i] = carry + v - orig;
        carry += __shfl(v, 63);
    }
    if (lane == 0) { bktStart[B] = carry; off[n] = E; }
}

// passB: scatter edges into bucket-major order, packed (dstl<<24 | src).
// int4-vectorized src/dst reads; scatter stores unchanged (bucket content is
// order-insensitive: per-node ranks were already atomic-race-ordered).
__global__ void passB(const int* __restrict__ src, const int* __restrict__ dst,
                      const int* __restrict__ G, const int* __restrict__ bktStart,
                      u32* __restrict__ bucketed, int E, int B) {
    __shared__ int baseS[BMAX];
    __shared__ int cnt[BMAX];
    int tx = threadIdx.x;
    for (int i = tx; i < B; i += 256) {
        baseS[i] = bktStart[i] + G[(size_t)blockIdx.x * B + i];
        cnt[i] = 0;
    }
    __syncthreads();
    int e0 = blockIdx.x * CH;
    int e1 = min(e0 + CH, E);
    for (int e = e0 + tx * 4; e < e1; e += 1024) {
        if (e + 4 <= e1) {
            int4 d4 = *(const int4*)(dst + e);
            int4 s4 = *(const int4*)(src + e);
            int b0 = d4.x >> S_BITS, b1 = d4.y >> S_BITS;
            int b2 = d4.z >> S_BITS, b3 = d4.w >> S_BITS;
            int r0 = atomicAdd(&cnt[b0], 1);
            int r1 = atomicAdd(&cnt[b1], 1);
            int r2 = atomicAdd(&cnt[b2], 1);
            int r3 = atomicAdd(&cnt[b3], 1);
            bucketed[baseS[b0] + r0] = ((u32)(d4.x & (S_NODES - 1)) << 24) | (u32)s4.x;
            bucketed[baseS[b1] + r1] = ((u32)(d4.y & (S_NODES - 1)) << 24) | (u32)s4.y;
            bucketed[baseS[b2] + r2] = ((u32)(d4.z & (S_NODES - 1)) << 24) | (u32)s4.z;
            bucketed[baseS[b3] + r3] = ((u32)(d4.w & (S_NODES - 1)) << 24) | (u32)s4.w;
        } else {
            for (int q = e; q < e1; ++q) {
                int d = dst[q];
                int b = d >> S_BITS;
                int r = atomicAdd(&cnt[b], 1);
                bucketed[baseS[b] + r] = ((u32)(d & (S_NODES - 1)) << 24) | (u32)src[q];
            }
        }
    }
}

// bucket_csr: one block per bucket. Count 256 local nodes, LDS scan -> off,
// then rank+place into final CSR. No global scan, no global atomics.
__global__ void bucket_csr(const u32* __restrict__ bucketed,
                           const int* __restrict__ bktStart,
                           int* __restrict__ off, int* __restrict__ csr,
                           int n) {
    __shared__ int degl[S_NODES];
    __shared__ int offl[S_NODES + 1];
    __shared__ int cntl[S_NODES];
    int b  = blockIdx.x;
    int tx = threadIdx.x;        // 256
    int bs = bktStart[b], be = bktStart[b + 1];
    degl[tx] = 0;
    cntl[tx] = 0;
    __syncthreads();
    for (int e = bs + tx; e < be; e += 256)
        atomicAdd(&degl[bucketed[e] >> 24], 1);      // LDS atomic
    __syncthreads();
    int v = degl[tx];
    offl[tx] = v;
    __syncthreads();
    for (int d = 1; d < 256; d <<= 1) {              // Hillis-Steele inclusive
        int t = (tx >= d) ? offl[tx - d] : 0;
        __syncthreads();
        offl[tx] += t;
        __syncthreads();
    }
    int excl = offl[tx] - v;
    __syncthreads();
    offl[tx] = excl;
    if (tx == 255) offl[256] = excl + v;
    __syncthreads();
    int node = b * S_NODES + tx;
    if (node <= n) off[node] = bs + offl[tx];
    for (int e = bs + tx; e < be; e += 256) {
        u32 w = bucketed[e];
        int dl = w >> 24;
        int r = atomicAdd(&cntl[dl], 1);             // LDS atomic
        csr[bs + offl[dl] + r] = (int)(w & 0xFFFFFFu);
    }
}

// ---------------- bf16 helpers ----------------
__device__ inline u16 f32_to_bf16_rne(float f) {
    u32 u = __float_as_uint(f);
    u += 0x7fffu + ((u >> 16) & 1u);
    return (u16)(u >> 16);
}

// Packed accumulate (round 10; codegen-neutral vs scalar, kept).
__device__ inline void accum8p(f32x2* a, uint4 w) {
    f32x2 v0 = { __uint_as_float(w.x << 16), __uint_as_float(w.x & 0xffff0000u) };
    f32x2 v1 = { __uint_as_float(w.y << 16), __uint_as_float(w.y & 0xffff0000u) };
    f32x2 v2 = { __uint_as_float(w.z << 16), __uint_as_float(w.z & 0xffff0000u) };
    f32x2 v3 = { __uint_as_float(w.w << 16), __uint_as_float(w.w & 0xffff0000u) };
    a[0] += v0;
    a[1] += v1;
    a[2] += v2;
    a[3] += v3;
}

__device__ inline float dot16(const float4* __restrict__ w, const float4* v) {
    float acc = 0.0f;
    #pragma unroll
    for (int k = 0; k < 16; ++k) {
        float4 a = w[k], b = v[k];
        acc += a.x * b.x + a.y * b.y + a.z * b.z + a.w * b.w;
    }
    return acc;
}

__device__ inline float dot10(const float4* __restrict__ w, const float4* v) {
    float acc = 0.0f;
    #pragma unroll
    for (int k = 0; k < 10; ++k) {
        float4 a = w[k], b = v[k];
        acc += a.x * b.x + a.y * b.y + a.z * b.z + a.w * b.w;
    }
    return acc;
}

// ---------------- pre1: xl = bf16(x@W1l^T), xr = x@W1r^T + b1 ----------------
// W1l|W1r (20.5KB) + b1 staged in LDS (round 5/9). LDS-staged coalesced
// writeout (round 3). __launch_bounds__(256) (round 4: prevents spill).
__global__ __launch_bounds__(256)
void pre1(const float* __restrict__ x, const float* __restrict__ W1l,
          const float* __restrict__ W1r, const float* __restrict__ b1,
          u32* __restrict__ xl, float* __restrict__ xr, int n) {
    __shared__ __align__(16) float Ws[80 * D_IN];           // 20.5 KB: rows 0..39=W1l, 40..79=W1r
    __shared__ float b1s[D_H];
    __shared__ __align__(16) u32   xl_s[128 * (D_H / 2)];   // 10 KB
    __shared__ __align__(16) float xr_s[128 * D_H];         // 20 KB
    int tx = threadIdx.x;
    {
        float4* wd = (float4*)Ws;
        for (int i = tx; i < 80 * 16; i += 256) {
            int r = i >> 4, c = i & 15;
            float4 v = (r < 40) ? ((const float4*)(W1l + r * D_IN))[c]
                                : ((const float4*)(W1r + (r - 40) * D_IN))[c];
            wd[i] = v;
        }
        if (tx < D_H) b1s[tx] = b1[tx];
    }
    __syncthreads();
    int m  = tx >> 1;            // local node 0..127
    int t  = tx & 1;             // half selector
    int node = blockIdx.x * 128 + m;
    if (node < n) {
        float4 xv[16];
        const float4* xp = (const float4*)(x + (size_t)node * D_IN);
        #pragma unroll
        for (int k = 0; k < 16; ++k) xv[k] = xp[k];
        #pragma unroll
        for (int k = 0; k < 10; ++k) {
            int o = t * 20 + 2 * k;
            float al0 = dot16((const float4*)(Ws + o * D_IN), xv);
            float al1 = dot16((const float4*)(Ws + (o + 1) * D_IN), xv);
            float ar0 = dot16((const float4*)(Ws + (40 + o) * D_IN), xv);
            float ar1 = dot16((const float4*)(Ws + (41 + o) * D_IN), xv);
            xl_s[m * (D_H / 2) + (o >> 1)] =
                (u32)f32_to_bf16_rne(al0) | ((u32)f32_to_bf16_rne(al1) << 16);
            xr_s[m * D_H + o]     = ar0 + b1s[o];
            xr_s[m * D_H + o + 1] = ar1 + b1s[o + 1];
        }
    }
    __syncthreads();
    int nb = min(128, n - blockIdx.x * 128);     // nodes in this block
    const uint4* sl = (const uint4*)xl_s;
    uint4* gl = (uint4*)(xl + (size_t)blockIdx.x * 128 * (D_H / 2));
    for (int i = tx; i < nb * 5; i += 256) gl[i] = sl[i];
    const float4* sr = (const float4*)xr_s;
    float4* gr = (float4*)(xr + (size_t)blockIdx.x * 128 * D_H);
    for (int i = tx; i < nb * 10; i += 256) gr[i] = sr[i];
}

// ---------------- Layer 1: h = relu(mean_gather(xl) + xr), in-place on xr ----
// Rounds 10/14: two VALU cuts both NULL (dur 55us, VALUBusy 50%, FETCH 172MB
// all byte-identical) -> not VALU-bound; Little's law says concurrency-starved
// (need ~230 in-flight loads/CU, have ~80; Occupancy only 65% from block churn:
// 25K blocks x ~2us lifetime). Fix (G11): grid-stride over node-quads with
// grid=2048 -> long-lived blocks, resident waves, latency overlap.
__global__ void gather_node1(const u32* __restrict__ xlp,
                             const int* __restrict__ off,
                             const int* __restrict__ csr,
                             float* __restrict__ hbuf,  // xr in, h out (n x 40)
                             int n) {
    __shared__ __align__(16) float part[4][12][D_H];
    int local = threadIdx.x >> 6;
    int lane  = threadIdx.x & 63;
    int g = lane / 5;
    int t = lane - g * 5;
    u32 tb = (u32)(t * 16);                  // byte offset of this lane's uint4
    const char* rowb = (const char*)xlp;     // 80 B per row
    int numQuads = (n + 3) >> 2;
    for (int q = blockIdx.x; q < numQuads; q += gridDim.x) {
        int node = q * 4 + local;
        int deg = 0;
        if (node < n) {
            int o0 = off[node], o1 = off[node + 1];
            deg = o1 - o0;
            f32x2 a0[4] = {{0,0},{0,0},{0,0},{0,0}};
            f32x2 a1[4] = {{0,0},{0,0},{0,0},{0,0}};
            f32x2 a2[4] = {{0,0},{0,0},{0,0},{0,0}};
            f32x2 a3[4] = {{0,0},{0,0},{0,0},{0,0}};
            for (int base = o0; base < o1; base += 64) {
                int cnt = min(64, o1 - base);
                int idx = (base + lane < o1) ? csr[base + lane] : 0;
                if (g < 12) {
                    for (int j = 0; j < cnt; j += 48) {
                        int j0 = j + g, j1 = j + 12 + g, j2 = j + 24 + g, j3 = j + 36 + g;
                        int s0 = __shfl(idx, j0 & 63);
                        int s1 = __shfl(idx, j1 & 63);
                        int s2 = __shfl(idx, j2 & 63);
                        int s3 = __shfl(idx, j3 & 63);
                        // Clamp dead slots onto s0's row (dup loads coalesce in
                        // L1/MSHR; all 4 loads unconditional -> MLP kept).
                        if (j1 >= cnt) s1 = s0;
                        if (j2 >= cnt) s2 = s0;
                        if (j3 >= cnt) s3 = s0;
                        u32 f0 = __umul24((u32)s0, 80u) + tb;
                        u32 f1 = __umul24((u32)s1, 80u) + tb;
                        u32 f2 = __umul24((u32)s2, 80u) + tb;
                        u32 f3 = __umul24((u32)s3, 80u) + tb;
                        uint4 w0 = *(const uint4*)(rowb + f0);
                        uint4 w1 = *(const uint4*)(rowb + f1);
                        uint4 w2 = *(const uint4*)(rowb + f2);
                        uint4 w3 = *(const uint4*)(rowb + f3);
                        if (j0 < cnt) accum8p(a0, w0);
                        if (j + 12 < cnt) { if (j1 < cnt) accum8p(a1, w1); }
                        if (j + 24 < cnt) { if (j2 < cnt) accum8p(a2, w2); }
                        if (j + 36 < cnt) { if (j3 < cnt) accum8p(a3, w3); }
                    }
                }
            }
            if (g < 12) {
                #pragma unroll
                for (int k = 0; k < 4; ++k) a0[k] += a1[k] + a2[k] + a3[k];
                f32x2* p = (f32x2*)&part[local][g][t * 8];
                p[0] = a0[0]; p[1] = a0[1]; p[2] = a0[2]; p[3] = a0[3];
            }
        }
        __syncthreads();
        if (node < n && lane < D_H) {
            float inv = 1.0f / fmaxf((float)deg, 1.0f);
            float agg = 0.0f;
            #pragma unroll
            for (int gg = 0; gg < 12; ++gg) agg += part[local][gg][lane];
            u32 p = __umul24((u32)node, (u32)D_H) + (u32)lane;
            hbuf[p] = fmaxf(agg * inv + hbuf[p], 0.0f);
        }
        __syncthreads();   // part consumed; safe to overwrite next iteration
    }
}

// ---------------- pre2: h2 = bf16(h@W2l^T) compact; hr = h@W2r^T + b2 --------
// Same W-in-LDS fix as pre1 (W2l|W2r = 7.7KB).
__global__ __launch_bounds__(256)
void pre2(float* __restrict__ hbuf, const float* __restrict__ W2l,
          const float* __restrict__ W2r, const float* __restrict__ b2,
          u32* __restrict__ h2, int n) {
    __shared__ __align__(16) float W2s[48 * D_H];            // 7.7 KB: rows 0..23=W2l, 24..47=W2r
    __shared__ float b2s[D_OUT];
    __shared__ __align__(16) u32   h2_s[128 * (D_OUT / 2)];  // 6 KB
    __shared__ __align__(16) float hr_s[128 * D_OUT];        // 12 KB
    int tx = threadIdx.x;
    {
        float4* wd = (float4*)W2s;
        for (int i = tx; i < 48 * 10; i += 256) {
            int r = i / 10, c = i - r * 10;
            float4 v = (r < 24) ? ((const float4*)(W2l + r * D_H))[c]
                                : ((const float4*)(W2r + (r - 24) * D_H))[c];
            wd[i] = v;
        }
        if (tx < D_OUT) b2s[tx] = b2[tx];
    }
    __syncthreads();
    int m  = tx >> 1;
    int t  = tx & 1;
    int node = blockIdx.x * 128 + m;
    if (node < n) {
        float4 hv[10];
        const float4* hp = (const float4*)(hbuf + (size_t)node * D_H);
        #pragma unroll
        for (int k = 0; k < 10; ++k) hv[k] = hp[k];
        #pragma unroll
        for (int k = 0; k < 6; ++k) {
            int o = t * 12 + 2 * k;
            float al0 = dot10((const float4*)(W2s + o * D_H), hv);
            float al1 = dot10((const float4*)(W2s + (o + 1) * D_H), hv);
            float ar0 = dot10((const float4*)(W2s + (24 + o) * D_H), hv);
            float ar1 = dot10((const float4*)(W2s + (25 + o) * D_H), hv);
            h2_s[m * (D_OUT / 2) + (o >> 1)] =
                (u32)f32_to_bf16_rne(al0) | ((u32)f32_to_bf16_rne(al1) << 16);
            hr_s[m * D_OUT + o]     = ar0 + b2s[o];
            hr_s[m * D_OUT + o + 1] = ar1 + b2s[o + 1];
        }
    }
    __syncthreads();
    int nb = min(128, n - blockIdx.x * 128);
    const uint4* sl = (const uint4*)h2_s;
    uint4* gl = (uint4*)(h2 + (size_t)blockIdx.x * 128 * (D_OUT / 2));
    for (int i = tx; i < nb * 3; i += 256) gl[i] = sl[i];
    const float4* sr = (const float4*)hr_s;
    float* grow = hbuf + (size_t)blockIdx.x * 128 * D_H;
    for (int i = tx; i < nb * 6; i += 256) {
        int nl = i / 6, c4 = i - nl * 6;
        *(float4*)(grow + (size_t)nl * D_H + c4 * 4) = sr[i];
    }
}

// ---------------- Layer 2: out = log_softmax(mean_gather(h2) + hr) -----------
// Same grid-stride wrapper as gather_node1 (rows 48 B).
__global__ void gather_node2(const u32* __restrict__ h2p,
                             const int* __restrict__ off,
                             const int* __restrict__ csr,
                             const float* __restrict__ hbuf,  // hr rows (stride 40)
                             float* __restrict__ out, int n) {
    __shared__ __align__(16) float part[4][21][D_OUT];
    int local = threadIdx.x >> 6;
    int lane  = threadIdx.x & 63;
    int g = lane / 3;
    int t = lane - g * 3;
    u32 tb = (u32)(t * 16);
    const char* rowb = (const char*)h2p;     // 48 B per row
    int numQuads = (n + 3) >> 2;
    for (int q = blockIdx.x; q < numQuads; q += gridDim.x) {
        int node = q * 4 + local;
        int deg = 0;
        if (node < n) {
            int o0 = off[node], o1 = off[node + 1];
            deg = o1 - o0;
            f32x2 a0[4] = {{0,0},{0,0},{0,0},{0,0}};
            f32x2 a1[4] = {{0,0},{0,0},{0,0},{0,0}};
            for (int base = o0; base < o1; base += 64) {
                int cnt = min(64, o1 - base);
                int idx = (base + lane < o1) ? csr[base + lane] : 0;
                if (g < 21) {
                    for (int j = 0; j < cnt; j += 42) {
                        int j0 = j + g, j1 = j + 21 + g;
                        int s0 = __shfl(idx, j0 & 63);
                        int s1 = __shfl(idx, j1 & 63);
                        if (j1 >= cnt) s1 = s0;   // clamp: dup load hits s0's line
                        u32 f0 = __umul24((u32)s0, 48u) + tb;
                        u32 f1 = __umul24((u32)s1, 48u) + tb;
                        uint4 w0 = *(const uint4*)(rowb + f0);
                        uint4 w1 = *(const uint4*)(rowb + f1);
                        if (j0 < cnt) accum8p(a0, w0);
                        if (j + 21 < cnt) { if (j1 < cnt) accum8p(a1, w1); }
                    }
                }
            }
            if (g < 21) {
                #pragma unroll
                for (int k = 0; k < 4; ++k) a0[k] += a1[k];
                f32x2* p = (f32x2*)&part[local][g][t * 8];
                p[0] = a0[0]; p[1] = a0[1]; p[2] = a0[2]; p[3] = a0[3];
            }
        }
        __syncthreads();
        // Wave-parallel log_softmax: lane k (k<24) holds its own logit;
        // 32-wide butterfly for max and sum (lanes 24..31 seeded -INF / 0).
        float val = 0.0f;
        if (node < n && lane < D_OUT) {
            float inv = 1.0f / fmaxf((float)deg, 1.0f);
            float agg = 0.0f;
            #pragma unroll
            for (int gg = 0; gg < 21; ++gg) agg += part[local][gg][lane];
            val = agg * inv + hbuf[__umul24((u32)node, (u32)D_H) + (u32)lane];
        }
        float m = (lane < D_OUT) ? val : -INFINITY;
        #pragma unroll
        for (int d = 16; d >= 1; d >>= 1) m = fmaxf(m, __shfl_xor(m, d, 32));
        float e = (lane < D_OUT) ? expf(val - m) : 0.0f;
        float se = e;
        #pragma unroll
        for (int d = 16; d >= 1; d >>= 1) se += __shfl_xor(se, d, 32);
        if (node < n && lane < D_OUT)
            out[__umul24((u32)node, (u32)D_OUT) + (u32)lane] = val - m - logf(se);
        __syncthreads();   // part consumed; safe to overwrite next iteration
    }
}

extern "C" void kernel_launch(void* const* d_in, const int* in_sizes, int n_in,
                              void* d_out, int out_size, void* d_ws, size_t ws_size,
                              hipStream_t stream) {
    const float* x   = (const float*)d_in[0];
    const int*   ei  = (const int*)d_in[1];
    const float* W1l = (const float*)d_in[2];
    const float* b1  = (const float*)d_in[3];
    const float* W1r = (const float*)d_in[4];
    const float* W2l = (const float*)d_in[5];
    const float* b2  = (const float*)d_in[6];
    const float* W2r = (const float*)d_in[7];
    float* out = (float*)d_out;

    const int n = in_sizes[0] / D_IN;      // 100000
    const int E = in_sizes[1] / 2;         // 3200000
    const int* src = ei;
    const int* dst = ei + E;

    const int B   = (n + S_NODES - 1) >> S_BITS;   // 391 buckets
    const int NB1 = (E + CH - 1) / CH;             // 391 edge blocks

    // Workspace (~38 MB):
    //  region0: n*40 f32 = 16 MB — bucketed (E u32, 12.8MB) then xr/h/hr (buf0)
    //  xl : n*40 bf16 = 8 MB — xl then h2 (compact n*24 bf16)
    //  off: (n+1) i32
    //  G  : NB1*B i32 ≈ 0.61 MB
    //  bktTotal: B i32 ; bktStart: (B+1) i32
    //  csr: E i32 = 12.8 MB
    char* ws = (char*)d_ws;
    float* buf0     = (float*)ws;
    u32*   bucketed = (u32*)ws;      ws += (size_t)n * D_H * 4;
    u16*   xl       = (u16*)ws;
    u16*   h2       = (u16*)ws;      ws += (size_t)n * D_H * 2;
    int*   off      = (int*)ws;      ws += (((size_t)(n + 1) * 4 + 15) & ~15ull);
    int*   G        = (int*)ws;      ws += (((size_t)NB1 * B * 4 + 15) & ~15ull);
    int*   bktTotal = (int*)ws;      ws += (((size_t)B * 4 + 15) & ~15ull);
    int*   bktStart = (int*)ws;      ws += (((size_t)(B + 1) * 4 + 15) & ~15ull);
    int*   csr      = (int*)ws;

    passA<<<NB1, 256, 0, stream>>>(dst, G, E, B);
    colscan<<<B, 64, 0, stream>>>(G, bktTotal, NB1, B);
    bucketscan<<<1, 64, 0, stream>>>(bktTotal, bktStart, off, B, E, n);
    passB<<<NB1, 256, 0, stream>>>(src, dst, G, bktStart, bucketed, E, B);
    bucket_csr<<<B, 256, 0, stream>>>(bucketed, bktStart, off, csr, n);

    const int numQuads = (n + 3) / 4;
    const int gatherGrid = numQuads < 2048 ? numQuads : 2048;   // G11: grid-stride

    pre1<<<(n + 127) / 128, 256, 0, stream>>>(x, W1l, W1r, b1, (u32*)xl, buf0, n);
    gather_node1<<<gatherGrid, 256, 0, stream>>>((const u32*)xl, off, csr, buf0, n);
    pre2<<<(n + 127) / 128, 256, 0, stream>>>(buf0, W2l, W2r, b2, (u32*)h2, n);
    gather_node2<<<gatherGrid, 256, 0, stream>>>((const u32*)h2, off, csr, buf0, out, n);
}

// Round 17
// 313.923 us; speedup vs baseline: 1.0443x; 1.0443x over previous
//
#include <hip/hip_runtime.h>
#include <math.h>

#define D_IN 64
#define D_H 40
#define D_OUT 24
#define S_BITS 8
#define S_NODES 256      // nodes per bucket
#define CH 8192          // edges per passA/passB block
#define BMAX 512         // max buckets (n <= 131072)

typedef unsigned int u32;
typedef unsigned short u16;
typedef __attribute__((ext_vector_type(2))) float f32x2;

// ---------------- CSR build: atomic-free LDS multisplit ----------------
__global__ void passA(const int* __restrict__ dst, int* __restrict__ G,
                      int E, int B) {
    __shared__ int hist[BMAX];
    int tx = threadIdx.x;
    for (int i = tx; i < B; i += 256) hist[i] = 0;
    __syncthreads();
    int e0 = blockIdx.x * CH;
    int e1 = min(e0 + CH, E);
    for (int e = e0 + tx * 4; e < e1; e += 1024) {
        if (e + 4 <= e1) {
            int4 d4 = *(const int4*)(dst + e);
            atomicAdd(&hist[d4.x >> S_BITS], 1);
            atomicAdd(&hist[d4.y >> S_BITS], 1);
            atomicAdd(&hist[d4.z >> S_BITS], 1);
            atomicAdd(&hist[d4.w >> S_BITS], 1);
        } else {
            for (int q = e; q < e1; ++q)
                atomicAdd(&hist[dst[q] >> S_BITS], 1);
        }
    }
    __syncthreads();
    for (int i = tx; i < B; i += 256) G[(size_t)blockIdx.x * B + i] = hist[i];
}

__global__ void colscan(int* __restrict__ G, int* __restrict__ bktTotal,
                        int NB1, int B) {
    int b = blockIdx.x;
    int lane = threadIdx.x;      // 64 threads
    int carry = 0;
    for (int base = 0; base < NB1; base += 64) {
        int i = base + lane;
        int orig = (i < NB1) ? G[(size_t)i * B + b] : 0;
        int v = orig;
        #pragma unroll
        for (int d = 1; d < 64; d <<= 1) {
            int t = __shfl_up(v, d);
            if (lane >= d) v += t;
        }
        if (i < NB1) G[(size_t)i * B + b] = carry + v - orig;   // exclusive
        carry += __shfl(v, 63);
    }
    if (lane == 0) bktTotal[b] = carry;
}

__global__ void bucketscan(const int* __restrict__ bktTotal,
                           int* __restrict__ bktStart, int* __restrict__ off,
                           int B, int E, int n) {
    int lane = threadIdx.x;
    int carry = 0;
    for (int base = 0; base < B; base += 64) {
        int i = base + lane;
        int orig = (i < B) ? bktTotal[i] : 0;
        int v = orig;
        #pragma unroll
        for (int d = 1; d < 64; d <<= 1) {
            int t = __shfl_up(v, d);
            if (lane >= d) v += t;
        }
        if (i < B) bktStart[i] = carry + v - orig;
        carry += __shfl(v, 63);
    }
    if (lane == 0) { bktStart[B] = carry; off[n] = E; }
}

__global__ void passB(const int* __restrict__ src, const int* __restrict__ dst,
                      const int* __restrict__ G, const int* __restrict__ bktStart,
                      u32* __restrict__ bucketed, int E, int B) {
    __shared__ int baseS[BMAX];
    __shared__ int cnt[BMAX];
    int tx = threadIdx.x;
    for (int i = tx; i < B; i += 256) {
        baseS[i] = bktStart[i] + G[(size_t)blockIdx.x * B + i];
        cnt[i] = 0;
    }
    __syncthreads();
    int e0 = blockIdx.x * CH;
    int e1 = min(e0 + CH, E);
    for (int e = e0 + tx * 4; e < e1; e += 1024) {
        if (e + 4 <= e1) {
            int4 d4 = *(const int4*)(dst + e);
            int4 s4 = *(const int4*)(src + e);
            int b0 = d4.x >> S_BITS, b1 = d4.y >> S_BITS;
            int b2 = d4.z >> S_BITS, b3 = d4.w >> S_BITS;
            int r0 = atomicAdd(&cnt[b0], 1);
            int r1 = atomicAdd(&cnt[b1], 1);
            int r2 = atomicAdd(&cnt[b2], 1);
            int r3 = atomicAdd(&cnt[b3], 1);
            bucketed[baseS[b0] + r0] = ((u32)(d4.x & (S_NODES - 1)) << 24) | (u32)s4.x;
            bucketed[baseS[b1] + r1] = ((u32)(d4.y & (S_NODES - 1)) << 24) | (u32)s4.y;
            bucketed[baseS[b2] + r2] = ((u32)(d4.z & (S_NODES - 1)) << 24) | (u32)s4.z;
            bucketed[baseS[b3] + r3] = ((u32)(d4.w & (S_NODES - 1)) << 24) | (u32)s4.w;
        } else {
            for (int q = e; q < e1; ++q) {
                int d = dst[q];
                int b = d >> S_BITS;
                int r = atomicAdd(&cnt[b], 1);
                bucketed[baseS[b] + r] = ((u32)(d & (S_NODES - 1)) << 24) | (u32)src[q];
            }
        }
    }
}

__global__ void bucket_csr(const u32* __restrict__ bucketed,
                           const int* __restrict__ bktStart,
                           int* __restrict__ off, int* __restrict__ csr,
                           int n) {
    __shared__ int degl[S_NODES];
    __shared__ int offl[S_NODES + 1];
    __shared__ int cntl[S_NODES];
    int b  = blockIdx.x;
    int tx = threadIdx.x;        // 256
    int bs = bktStart[b], be = bktStart[b + 1];
    degl[tx] = 0;
    cntl[tx] = 0;
    __syncthreads();
    for (int e = bs + tx; e < be; e += 256)
        atomicAdd(&degl[bucketed[e] >> 24], 1);      // LDS atomic
    __syncthreads();
    int v = degl[tx];
    offl[tx] = v;
    __syncthreads();
    for (int d = 1; d < 256; d <<= 1) {              // Hillis-Steele inclusive
        int t = (tx >= d) ? offl[tx - d] : 0;
        __syncthreads();
        offl[tx] += t;
        __syncthreads();
    }
    int excl = offl[tx] - v;
    __syncthreads();
    offl[tx] = excl;
    if (tx == 255) offl[256] = excl + v;
    __syncthreads();
    int node = b * S_NODES + tx;
    if (node <= n) off[node] = bs + offl[tx];
    for (int e = bs + tx; e < be; e += 256) {
        u32 w = bucketed[e];
        int dl = w >> 24;
        int r = atomicAdd(&cntl[dl], 1);             // LDS atomic
        csr[bs + offl[dl] + r] = (int)(w & 0xFFFFFFu);
    }
}

// ---------------- bf16 helpers ----------------
__device__ inline u16 f32_to_bf16_rne(float f) {
    u32 u = __float_as_uint(f);
    u += 0x7fffu + ((u >> 16) & 1u);
    return (u16)(u >> 16);
}

// Packed accumulate (round 10; codegen-neutral vs scalar, kept).
__device__ inline void accum8p(f32x2* a, uint4 w) {
    f32x2 v0 = { __uint_as_float(w.x << 16), __uint_as_float(w.x & 0xffff0000u) };
    f32x2 v1 = { __uint_as_float(w.y << 16), __uint_as_float(w.y & 0xffff0000u) };
    f32x2 v2 = { __uint_as_float(w.z << 16), __uint_as_float(w.z & 0xffff0000u) };
    f32x2 v3 = { __uint_as_float(w.w << 16), __uint_as_float(w.w & 0xffff0000u) };
    a[0] += v0;
    a[1] += v1;
    a[2] += v2;
    a[3] += v3;
}

__device__ inline float dot16(const float4* __restrict__ w, const float4* v) {
    float acc = 0.0f;
    #pragma unroll
    for (int k = 0; k < 16; ++k) {
        float4 a = w[k], b = v[k];
        acc += a.x * b.x + a.y * b.y + a.z * b.z + a.w * b.w;
    }
    return acc;
}

__device__ inline float dot10(const float4* __restrict__ w, const float4* v) {
    float acc = 0.0f;
    #pragma unroll
    for (int k = 0; k < 10; ++k) {
        float4 a = w[k], b = v[k];
        acc += a.x * b.x + a.y * b.y + a.z * b.z + a.w * b.w;
    }
    return acc;
}

// ---------------- pre1: xl = bf16(x@W1l^T), xr = x@W1r^T + b1 ----------------
// W1l|W1r (20.5KB) + b1 staged in LDS (round 5/9). LDS-staged coalesced
// writeout (round 3). __launch_bounds__(256) (round 4: prevents spill).
__global__ __launch_bounds__(256)
void pre1(const float* __restrict__ x, const float* __restrict__ W1l,
          const float* __restrict__ W1r, const float* __restrict__ b1,
          u32* __restrict__ xl, float* __restrict__ xr, int n) {
    __shared__ __align__(16) float Ws[80 * D_IN];           // 20.5 KB: rows 0..39=W1l, 40..79=W1r
    __shared__ float b1s[D_H];
    __shared__ __align__(16) u32   xl_s[128 * (D_H / 2)];   // 10 KB
    __shared__ __align__(16) float xr_s[128 * D_H];         // 20 KB
    int tx = threadIdx.x;
    {
        float4* wd = (float4*)Ws;
        for (int i = tx; i < 80 * 16; i += 256) {
            int r = i >> 4, c = i & 15;
            float4 v = (r < 40) ? ((const float4*)(W1l + r * D_IN))[c]
                                : ((const float4*)(W1r + (r - 40) * D_IN))[c];
            wd[i] = v;
        }
        if (tx < D_H) b1s[tx] = b1[tx];
    }
    __syncthreads();
    int m  = tx >> 1;            // local node 0..127
    int t  = tx & 1;             // half selector
    int node = blockIdx.x * 128 + m;
    if (node < n) {
        float4 xv[16];
        const float4* xp = (const float4*)(x + (size_t)node * D_IN);
        #pragma unroll
        for (int k = 0; k < 16; ++k) xv[k] = xp[k];
        #pragma unroll
        for (int k = 0; k < 10; ++k) {
            int o = t * 20 + 2 * k;
            float al0 = dot16((const float4*)(Ws + o * D_IN), xv);
            float al1 = dot16((const float4*)(Ws + (o + 1) * D_IN), xv);
            float ar0 = dot16((const float4*)(Ws + (40 + o) * D_IN), xv);
            float ar1 = dot16((const float4*)(Ws + (41 + o) * D_IN), xv);
            xl_s[m * (D_H / 2) + (o >> 1)] =
                (u32)f32_to_bf16_rne(al0) | ((u32)f32_to_bf16_rne(al1) << 16);
            xr_s[m * D_H + o]     = ar0 + b1s[o];
            xr_s[m * D_H + o + 1] = ar1 + b1s[o + 1];
        }
    }
    __syncthreads();
    int nb = min(128, n - blockIdx.x * 128);     // nodes in this block
    const uint4* sl = (const uint4*)xl_s;
    uint4* gl = (uint4*)(xl + (size_t)blockIdx.x * 128 * (D_H / 2));
    for (int i = tx; i < nb * 5; i += 256) gl[i] = sl[i];
    const float4* sr = (const float4*)xr_s;
    float4* gr = (float4*)(xr + (size_t)blockIdx.x * 128 * D_H);
    for (int i = tx; i < nb * 10; i += 256) gr[i] = sr[i];
}

// ---------------- Layer 1: h = relu(mean_gather(xl) + xr), in-place on xr ----
// Measured-best form (round 10: 55us). Three experiments concluded: VALU cuts
// x2 = NULL (not VALU-bound), grid-stride = regression (load imbalance).
// g1 sits near the random-gather L2/L3 ceiling: 172MB L2-miss at ~3.3TB/s,
// ~33% L2 hit on 8MB xl vs 4MB per-XCD L2 -- arithmetic matches.
__global__ void gather_node1(const u32* __restrict__ xlp,
                             const int* __restrict__ off,
                             const int* __restrict__ csr,
                             float* __restrict__ hbuf,  // xr in, h out (n x 40)
                             int n) {
    __shared__ __align__(16) float part[4][12][D_H];
    int local = threadIdx.x >> 6;
    int lane  = threadIdx.x & 63;
    int node  = blockIdx.x * 4 + local;
    int g = lane / 5;
    int t = lane - g * 5;
    u32 tb = (u32)(t * 16);                  // byte offset of this lane's uint4
    int deg = 0;
    const char* rowb = (const char*)xlp;     // 80 B per row
    if (node < n) {
        int o0 = off[node], o1 = off[node + 1];
        deg = o1 - o0;
        f32x2 a0[4] = {{0,0},{0,0},{0,0},{0,0}};
        f32x2 a1[4] = {{0,0},{0,0},{0,0},{0,0}};
        f32x2 a2[4] = {{0,0},{0,0},{0,0},{0,0}};
        f32x2 a3[4] = {{0,0},{0,0},{0,0},{0,0}};
        for (int base = o0; base < o1; base += 64) {
            int cnt = min(64, o1 - base);
            int idx = (base + lane < o1) ? csr[base + lane] : 0;
            if (g < 12) {
                for (int j = 0; j < cnt; j += 48) {
                    int j0 = j + g, j1 = j + 12 + g, j2 = j + 24 + g, j3 = j + 36 + g;
                    int s0 = __shfl(idx, j0 & 63);
                    int s1 = __shfl(idx, j1 & 63);
                    int s2 = __shfl(idx, j2 & 63);
                    int s3 = __shfl(idx, j3 & 63);
                    // Clamp dead slots onto s0's row (dup loads coalesce in
                    // L1/MSHR; all 4 loads unconditional -> MLP kept).
                    if (j1 >= cnt) s1 = s0;
                    if (j2 >= cnt) s2 = s0;
                    if (j3 >= cnt) s3 = s0;
                    u32 f0 = __umul24((u32)s0, 80u) + tb;
                    u32 f1 = __umul24((u32)s1, 80u) + tb;
                    u32 f2 = __umul24((u32)s2, 80u) + tb;
                    u32 f3 = __umul24((u32)s3, 80u) + tb;
                    uint4 w0 = *(const uint4*)(rowb + f0);
                    uint4 w1 = *(const uint4*)(rowb + f1);
                    uint4 w2 = *(const uint4*)(rowb + f2);
                    uint4 w3 = *(const uint4*)(rowb + f3);
                    if (j0 < cnt) accum8p(a0, w0);
                    if (j + 12 < cnt) { if (j1 < cnt) accum8p(a1, w1); }
                    if (j + 24 < cnt) { if (j2 < cnt) accum8p(a2, w2); }
                    if (j + 36 < cnt) { if (j3 < cnt) accum8p(a3, w3); }
                }
            }
        }
        if (g < 12) {
            #pragma unroll
            for (int k = 0; k < 4; ++k) a0[k] += a1[k] + a2[k] + a3[k];
            f32x2* p = (f32x2*)&part[local][g][t * 8];
            p[0] = a0[0]; p[1] = a0[1]; p[2] = a0[2]; p[3] = a0[3];
        }
    }
    __syncthreads();
    if (node < n && lane < D_H) {
        float inv = 1.0f / fmaxf((float)deg, 1.0f);
        float agg = 0.0f;
        #pragma unroll
        for (int gg = 0; gg < 12; ++gg) agg += part[local][gg][lane];
        u32 p = __umul24((u32)node, (u32)D_H) + (u32)lane;
        hbuf[p] = fmaxf(agg * inv + hbuf[p], 0.0f);
    }
}

// ---------------- pre2: h2 = bf16(h@W2l^T) compact; hr = h@W2r^T + b2 --------
// Same W-in-LDS fix as pre1 (W2l|W2r = 7.7KB).
__global__ __launch_bounds__(256)
void pre2(float* __restrict__ hbuf, const float* __restrict__ W2l,
          const float* __restrict__ W2r, const float* __restrict__ b2,
          u32* __restrict__ h2, int n) {
    __shared__ __align__(16) float W2s[48 * D_H];            // 7.7 KB: rows 0..23=W2l, 24..47=W2r
    __shared__ float b2s[D_OUT];
    __shared__ __align__(16) u32   h2_s[128 * (D_OUT / 2)];  // 6 KB
    __shared__ __align__(16) float hr_s[128 * D_OUT];        // 12 KB
    int tx = threadIdx.x;
    {
        float4* wd = (float4*)W2s;
        for (int i = tx; i < 48 * 10; i += 256) {
            int r = i / 10, c = i - r * 10;
            float4 v = (r < 24) ? ((const float4*)(W2l + r * D_H))[c]
                                : ((const float4*)(W2r + (r - 24) * D_H))[c];
            wd[i] = v;
        }
        if (tx < D_OUT) b2s[tx] = b2[tx];
    }
    __syncthreads();
    int m  = tx >> 1;
    int t  = tx & 1;
    int node = blockIdx.x * 128 + m;
    if (node < n) {
        float4 hv[10];
        const float4* hp = (const float4*)(hbuf + (size_t)node * D_H);
        #pragma unroll
        for (int k = 0; k < 10; ++k) hv[k] = hp[k];
        #pragma unroll
        for (int k = 0; k < 6; ++k) {
            int o = t * 12 + 2 * k;
            float al0 = dot10((const float4*)(W2s + o * D_H), hv);
            float al1 = dot10((const float4*)(W2s + (o + 1) * D_H), hv);
            float ar0 = dot10((const float4*)(W2s + (24 + o) * D_H), hv);
            float ar1 = dot10((const float4*)(W2s + (25 + o) * D_H), hv);
            h2_s[m * (D_OUT / 2) + (o >> 1)] =
                (u32)f32_to_bf16_rne(al0) | ((u32)f32_to_bf16_rne(al1) << 16);
            hr_s[m * D_OUT + o]     = ar0 + b2s[o];
            hr_s[m * D_OUT + o + 1] = ar1 + b2s[o + 1];
        }
    }
    __syncthreads();
    int nb = min(128, n - blockIdx.x * 128);
    const uint4* sl = (const uint4*)h2_s;
    uint4* gl = (uint4*)(h2 + (size_t)blockIdx.x * 128 * (D_OUT / 2));
    for (int i = tx; i < nb * 3; i += 256) gl[i] = sl[i];
    const float4* sr = (const float4*)hr_s;
    float* grow = hbuf + (size_t)blockIdx.x * 128 * D_H;
    for (int i = tx; i < nb * 6; i += 256) {
        int nl = i / 6, c4 = i - nl * 6;
        *(float4*)(grow + (size_t)nl * D_H + c4 * 4) = sr[i];
    }
}

// ---------------- Layer 2: out = log_softmax(mean_gather(h2) + hr) -----------
// Measured-best form (round 10), rows 48 B.
__global__ void gather_node2(const u32* __restrict__ h2p,
                             const int* __restrict__ off,
                             const int* __restrict__ csr,
                             const float* __restrict__ hbuf,  // hr rows (stride 40)
                             float* __restrict__ out, int n) {
    __shared__ __align__(16) float part[4][21][D_OUT];
    int local = threadIdx.x >> 6;
    int lane  = threadIdx.x & 63;
    int node  = blockIdx.x * 4 + local;
    int g = lane / 3;
    int t = lane - g * 3;
    u32 tb = (u32)(t * 16);
    int deg = 0;
    const char* rowb = (const char*)h2p;     // 48 B per row
    if (node < n) {
        int o0 = off[node], o1 = off[node + 1];
        deg = o1 - o0;
        f32x2 a0[4] = {{0,0},{0,0},{0,0},{0,0}};
        f32x2 a1[4] = {{0,0},{0,0},{0,0},{0,0}};
        for (int base = o0; base < o1; base += 64) {
            int cnt = min(64, o1 - base);
            int idx = (base + lane < o1) ? csr[base + lane] : 0;
            if (g < 21) {
                for (int j = 0; j < cnt; j += 42) {
                    int j0 = j + g, j1 = j + 21 + g;
                    int s0 = __shfl(idx, j0 & 63);
                    int s1 = __shfl(idx, j1 & 63);
                    if (j1 >= cnt) s1 = s0;   // clamp: dup load hits s0's line
                    u32 f0 = __umul24((u32)s0, 48u) + tb;
                    u32 f1 = __umul24((u32)s1, 48u) + tb;
                    uint4 w0 = *(const uint4*)(rowb + f0);
                    uint4 w1 = *(const uint4*)(rowb + f1);
                    if (j0 < cnt) accum8p(a0, w0);
                    if (j + 21 < cnt) { if (j1 < cnt) accum8p(a1, w1); }
                }
            }
        }
        if (g < 21) {
            #pragma unroll
            for (int k = 0; k < 4; ++k) a0[k] += a1[k];
            f32x2* p = (f32x2*)&part[local][g][t * 8];
            p[0] = a0[0]; p[1] = a0[1]; p[2] = a0[2]; p[3] = a0[3];
        }
    }
    __syncthreads();
    // Wave-parallel log_softmax: lane k (k<24) holds its own logit in a register;
    // 32-wide butterfly for max and sum (lanes 24..31 seeded -INF / 0).
    float val = 0.0f;
    if (node < n && lane < D_OUT) {
        float inv = 1.0f / fmaxf((float)deg, 1.0f);
        float agg = 0.0f;
        #pragma unroll
        for (int gg = 0; gg < 21; ++gg) agg += part[local][gg][lane];
        val = agg * inv + hbuf[__umul24((u32)node, (u32)D_H) + (u32)lane];
    }
    float m = (lane < D_OUT) ? val : -INFINITY;
    #pragma unroll
    for (int d = 16; d >= 1; d >>= 1) m = fmaxf(m, __shfl_xor(m, d, 32));
    float e = (lane < D_OUT) ? expf(val - m) : 0.0f;
    float se = e;
    #pragma unroll
    for (int d = 16; d >= 1; d >>= 1) se += __shfl_xor(se, d, 32);
    if (node < n && lane < D_OUT)
        out[__umul24((u32)node, (u32)D_OUT) + (u32)lane] = val - m - logf(se);
}

extern "C" void kernel_launch(void* const* d_in, const int* in_sizes, int n_in,
                              void* d_out, int out_size, void* d_ws, size_t ws_size,
                              hipStream_t stream) {
    const float* x   = (const float*)d_in[0];
    const int*   ei  = (const int*)d_in[1];
    const float* W1l = (const float*)d_in[2];
    const float* b1  = (const float*)d_in[3];
    const float* W1r = (const float*)d_in[4];
    const float* W2l = (const float*)d_in[5];
    const float* b2  = (const float*)d_in[6];
    const float* W2r = (const float*)d_in[7];
    float* out = (float*)d_out;

    const int n = in_sizes[0] / D_IN;      // 100000
    const int E = in_sizes[1] / 2;         // 3200000
    const int* src = ei;
    const int* dst = ei + E;

    const int B   = (n + S_NODES - 1) >> S_BITS;   // 391 buckets
    const int NB1 = (E + CH - 1) / CH;             // 391 edge blocks

    // Workspace (~38 MB):
    //  region0: n*40 f32 = 16 MB — bucketed (E u32, 12.8MB) then xr/h/hr (buf0)
    //  xl : n*40 bf16 = 8 MB — xl then h2 (compact n*24 bf16)
    //  off: (n+1) i32
    //  G  : NB1*B i32 ≈ 0.61 MB
    //  bktTotal: B i32 ; bktStart: (B+1) i32
    //  csr: E i32 = 12.8 MB
    char* ws = (char*)d_ws;
    float* buf0     = (float*)ws;
    u32*   bucketed = (u32*)ws;      ws += (size_t)n * D_H * 4;
    u16*   xl       = (u16*)ws;
    u16*   h2       = (u16*)ws;      ws += (size_t)n * D_H * 2;
    int*   off      = (int*)ws;      ws += (((size_t)(n + 1) * 4 + 15) & ~15ull);
    int*   G        = (int*)ws;      ws += (((size_t)NB1 * B * 4 + 15) & ~15ull);
    int*   bktTotal = (int*)ws;      ws += (((size_t)B * 4 + 15) & ~15ull);
    int*   bktStart = (int*)ws;      ws += (((size_t)(B + 1) * 4 + 15) & ~15ull);
    int*   csr      = (int*)ws;

    passA<<<NB1, 256, 0, stream>>>(dst, G, E, B);
    colscan<<<B, 64, 0, stream>>>(G, bktTotal, NB1, B);
    bucketscan<<<1, 64, 0, stream>>>(bktTotal, bktStart, off, B, E, n);
    passB<<<NB1, 256, 0, stream>>>(src, dst, G, bktStart, bucketed, E, B);
    bucket_csr<<<B, 256, 0, stream>>>(bucketed, bktStart, off, csr, n);

    pre1<<<(n + 127) / 128, 256, 0, stream>>>(x, W1l, W1r, b1, (u32*)xl, buf0, n);
    gather_node1<<<(n + 3) / 4, 256, 0, stream>>>((const u32*)xl, off, csr, buf0, n);
    pre2<<<(n + 127) / 128, 256, 0, stream>>>(buf0, W2l, W2r, b2, (u32*)h2, n);
    gather_node2<<<(n + 3) / 4, 256, 0, stream>>>((const u32*)h2, off, csr, buf0, out, n);
}